// Round 7
// baseline (197.267 us; speedup 1.0000x reference)
//
#include <hip/hip_runtime.h>
#include <math.h>

// ws layout (float offsets)
#define PA_OFF    0        // 25088  patch_grad row-sums, pa[p*128 + b]
#define APOOL_OFF 25600    // 588    attack_w mean-pool, k = c*196 + px*14 + py
#define MA_OFF    26624    // 588    masked attack pool
#define IPOOL_OFF 28672    // 75264  input mean-pool [128 b][588 k]
#define PL_OFF    106496   // 1048576 logits partials [8 ksplit][128 b][1024 n]

typedef float v4f __attribute__((ext_vector_type(4)));

__device__ __forceinline__ float hsum4(v4f v) { return (v.x + v.y) + (v.z + v.w); }

// ---------------------------------------------------------------------------
// K1: both 77MB streams, nontemporal loads, max-depth batches, 12 waves/CU.
//   blocks [0,784):     patch_grad row sums — one wave per 8 rows; 24 float4
//                       nt loads issued as one batch before consumption.
//   blocks [784,2139):  input/attack mean-pool — one wave per (img,px) strip,
//                       16-load nt batch.
// History: 6 structural variants (serial, LDS-staged, autonomous, dbuf,
// pinned batches, nt) land 55-59 us until nt loads: now <45.6 us. Remaining
// gap vs 6.7 TB/s bus attributed to concurrent harness restore writeback.
__global__ __launch_bounds__(256, 3) void k1_main(
    const float* __restrict__ inputs,
    const float* __restrict__ patch_grad,
    const float* __restrict__ attack_w,
    float* __restrict__ ws)
{
  const int bid  = blockIdx.x;
  const int lane = threadIdx.x & 63;

  if (bid < 784) {
    const int w  = bid * 4 + (threadIdx.x >> 6);   // 0..3135
    const int R0 = w * 8;                           // 8 rows of 768 floats
    const v4f* src = (const v4f*)patch_grad + (size_t)R0 * 192 + lane;

    v4f v[24];
    #pragma unroll
    for (int j = 0; j < 24; ++j)
      v[j] = __builtin_nontemporal_load(src + (size_t)j * 64);
    __builtin_amdgcn_sched_barrier(0);

    float s[8];
    #pragma unroll
    for (int k = 0; k < 8; ++k)
      s[k] = hsum4(v[3 * k]) + hsum4(v[3 * k + 1]) + hsum4(v[3 * k + 2]);

    #pragma unroll
    for (int o = 32; o > 0; o >>= 1) {
      #pragma unroll
      for (int k = 0; k < 8; ++k) s[k] += __shfl_down(s[k], o, 64);
    }
    if (lane == 0) {
      float* pa = ws + PA_OFF;
      #pragma unroll
      for (int k = 0; k < 8; ++k) {
        const int row = R0 + k, b = row / 196, p = row - b * 196;
        __builtin_nontemporal_store(s[k], &pa[p * 128 + b]);
      }
    }
  } else {
    const int w = (bid - 784) * 4 + (threadIdx.x >> 6);
    if (w >= 5418) return;                        // 387 imgs * 14 px
    const int img = w / 14, px = w - img * 14;
    const float* base = (img < 384)
        ? inputs + (size_t)img * 50176
        : attack_w + (size_t)(img - 384) * 50176;
    const v4f* src = (const v4f*)(base + px * 3584);
    const int cl = (lane < 56) ? lane : 55;       // clamp: no divergent load path

    v4f v[16];
    #pragma unroll
    for (int r = 0; r < 16; ++r)
      v[r] = __builtin_nontemporal_load(src + r * 56 + cl);
    __builtin_amdgcn_sched_barrier(0);

    v4f s = v[0];
    #pragma unroll
    for (int r = 1; r < 16; ++r) s += v[r];
    // sum across the 4 lanes of each py group (lanes 4*py .. 4*py+3)
    s.x += __shfl_xor(s.x, 1); s.y += __shfl_xor(s.y, 1);
    s.z += __shfl_xor(s.z, 1); s.w += __shfl_xor(s.w, 1);
    s.x += __shfl_xor(s.x, 2); s.y += __shfl_xor(s.y, 2);
    s.z += __shfl_xor(s.z, 2); s.w += __shfl_xor(s.w, 2);
    if ((lane & 3) == 0 && lane < 56) {
      const int py = lane >> 2;
      const float ps = ((s.x + s.y) + (s.z + s.w)) * (1.f / 256.f);
      if (img < 384) {
        const int b = img / 3, c = img - b * 3;
        __builtin_nontemporal_store(
            ps, &ws[IPOOL_OFF + (size_t)b * 588 + c * 196 + px * 14 + py]);
      } else {
        ws[APOOL_OFF + (img - 384) * 196 + px * 14 + py] = ps;
      }
    }
  }
}

// ---------------------------------------------------------------------------
// K2: reduce pa over b, top-20 rank selection, masked attack pool; zero loss.
__global__ __launch_bounds__(256) void k2_topk(float* __restrict__ ws,
                                               float* __restrict__ d_loss)
{
  __shared__ float sp[196];
  __shared__ float maskp[196];
  const int t = threadIdx.x;
  if (t < 196) {
    const float4* q = (const float4*)(ws + PA_OFF + (size_t)t * 128);
    float4 a = make_float4(0.f, 0.f, 0.f, 0.f);
    #pragma unroll
    for (int j = 0; j < 32; ++j) {
      const float4 v = q[j];
      a.x += v.x; a.y += v.y; a.z += v.z; a.w += v.w;
    }
    sp[t] = (a.x + a.y) + (a.z + a.w);
  }
  if (t == 0) *d_loss = 0.f;
  __syncthreads();
  if (t < 196) {
    const float v = sp[t];
    int cnt = 0;
    for (int j = 0; j < 196; ++j) {
      const float u = sp[j];
      cnt += (u > v || (u == v && j < t)) ? 1 : 0;   // rank with index tie-break
    }
    maskp[t] = (cnt < 20) ? 1.f : 0.f;
  }
  __syncthreads();
  for (int k = t; k < 588; k += 256) {
    const int p = k % 196;
    ws[MA_OFF + k] = maskp[p] * ws[APOOL_OFF + k];
  }
}

// ---------------------------------------------------------------------------
// K3: logits = (ipool + ma) @ w_cls, split-K=8 into partials.
// bid = (bg*16 + nt)*8 + ks : bg in [0,16) (8 b's), nt in [0,16) (64 n's),
// ks in [0,8) (74 k's, last slice 70). LDS tile stride 9 -> <=2-way aliasing
// on staging (free per m136), wave-uniform broadcast on reads.
__global__ __launch_bounds__(256) void k3_gemm(const float* __restrict__ w_cls,
                                               float* __restrict__ ws)
{
  __shared__ __align__(16) float lp[74 * 9];
  const int bid = blockIdx.x;
  const int ks = bid & 7;
  const int nt = (bid >> 3) & 15;
  const int bg = bid >> 7;
  const int t  = threadIdx.x;
  const int kk_max = (ks == 7) ? 70 : 74;
  const float* ipool = ws + IPOOL_OFF;
  const float* ma    = ws + MA_OFF;
  for (int idx = t; idx < 592; idx += 256) {
    const int bb = idx & 7;
    const int kk = idx >> 3;
    const int k  = ks * 74 + kk;
    lp[kk * 9 + bb] = (kk < kk_max)
        ? ipool[(size_t)(bg * 8 + bb) * 588 + k] + ma[k]
        : 0.f;
  }
  __syncthreads();
  const int lane = t & 63, g = t >> 6;
  const int n = nt * 64 + lane;
  const bool valid = n < 1000;
  float a0 = 0, a1 = 0;
  const float* wc = w_cls + (size_t)ks * 74 * 1000 + n;
  #pragma unroll 10
  for (int kk = 0; kk < kk_max; ++kk) {
    const float w = valid ? wc[(size_t)kk * 1000] : 0.f;
    const float2 pv = *(const float2*)&lp[kk * 9 + g * 2];  // wave-uniform -> broadcast
    a0 += pv.x * w; a1 += pv.y * w;
  }
  float* pl = ws + PL_OFF;
  const int rowb = bg * 8 + g * 2;
  __builtin_nontemporal_store(a0, &pl[(size_t)(ks * 128 + rowb + 0) * 1024 + n]);
  __builtin_nontemporal_store(a1, &pl[(size_t)(ks * 128 + rowb + 1) * 1024 + n]);
}

// ---------------------------------------------------------------------------
// K4: sum 8 split-K partials -> logits; softmax -> prob (output 0);
// log_softmax(prob) -> ce -> loss atomic.
__global__ __launch_bounds__(256) void k4_softmax(const float* __restrict__ ws,
                                                  const int* __restrict__ targets,
                                                  float* __restrict__ out)
{
  __shared__ float red[4];
  __shared__ float sh_pt;
  const int b = blockIdx.x, t = threadIdx.x;
  const float* pl = ws + PL_OFF;
  float l[4]; bool val[4];
  #pragma unroll
  for (int j = 0; j < 4; ++j) {
    const int n = j * 256 + t;
    val[j] = (n < 1000);
    float s = -INFINITY;
    if (val[j]) {
      s = 0.f;
      #pragma unroll
      for (int ks = 0; ks < 8; ++ks) s += pl[(size_t)(ks * 128 + b) * 1024 + n];
    }
    l[j] = s;
  }
  float m = fmaxf(fmaxf(l[0], l[1]), fmaxf(l[2], l[3]));
  #pragma unroll
  for (int o = 32; o > 0; o >>= 1) m = fmaxf(m, __shfl_down(m, o, 64));
  if ((t & 63) == 0) red[t >> 6] = m;
  __syncthreads();
  const float m1 = fmaxf(fmaxf(red[0], red[1]), fmaxf(red[2], red[3]));
  __syncthreads();
  float e[4]; float s = 0.f;
  #pragma unroll
  for (int j = 0; j < 4; ++j) { e[j] = val[j] ? expf(l[j] - m1) : 0.f; s += e[j]; }
  #pragma unroll
  for (int o = 32; o > 0; o >>= 1) s += __shfl_down(s, o, 64);
  if ((t & 63) == 0) red[t >> 6] = s;
  __syncthreads();
  const float S1 = red[0] + red[1] + red[2] + red[3];
  __syncthreads();
  const float inv = 1.f / S1;
  const int tgt = targets[b];
  float p[4];
  #pragma unroll
  for (int j = 0; j < 4; ++j) {
    const int n = j * 256 + t;
    if (val[j]) {
      p[j] = e[j] * inv;
      out[(size_t)b * 1000 + n] = p[j];
      if (n == tgt) sh_pt = p[j];
    } else {
      p[j] = -INFINITY;
    }
  }
  float m2 = fmaxf(fmaxf(p[0], p[1]), fmaxf(p[2], p[3]));
  #pragma unroll
  for (int o = 32; o > 0; o >>= 1) m2 = fmaxf(m2, __shfl_down(m2, o, 64));
  if ((t & 63) == 0) red[t >> 6] = m2;
  __syncthreads();
  const float M2 = fmaxf(fmaxf(red[0], red[1]), fmaxf(red[2], red[3]));
  __syncthreads();
  float s2 = 0.f;
  #pragma unroll
  for (int j = 0; j < 4; ++j) s2 += val[j] ? expf(p[j] - M2) : 0.f;
  #pragma unroll
  for (int o = 32; o > 0; o >>= 1) s2 += __shfl_down(s2, o, 64);
  if ((t & 63) == 0) red[t >> 6] = s2;
  __syncthreads();
  if (t == 0) {
    const float S2 = red[0] + red[1] + red[2] + red[3];
    const float lse2 = M2 + logf(S2);
    atomicAdd(out + 128000, (sh_pt - lse2) * (1.f / 128.f));
  }
}

// ---------------------------------------------------------------------------
extern "C" void kernel_launch(void* const* d_in, const int* in_sizes, int n_in,
                              void* d_out, int out_size, void* d_ws, size_t ws_size,
                              hipStream_t stream) {
  const float* inputs     = (const float*)d_in[0];
  const float* patch_grad = (const float*)d_in[1];
  const float* attack_w   = (const float*)d_in[2];
  const float* w_cls      = (const float*)d_in[3];
  const int*   targets    = (const int*)d_in[4];
  float* out = (float*)d_out;
  float* ws  = (float*)d_ws;

  hipLaunchKernelGGL(k1_main,  dim3(2139), dim3(256), 0, stream,
                     inputs, patch_grad, attack_w, ws);
  hipLaunchKernelGGL(k2_topk,  dim3(1),    dim3(256), 0, stream, ws, out + 128000);
  hipLaunchKernelGGL(k3_gemm,  dim3(2048), dim3(256), 0, stream, w_cls, ws);
  hipLaunchKernelGGL(k4_softmax, dim3(128), dim3(256), 0, stream, ws, targets, out);
}

// Round 8
// 188.731 us; speedup vs baseline: 1.0452x; 1.0452x over previous
//
#include <hip/hip_runtime.h>
#include <math.h>

// ws layout (float offsets)
#define PA_OFF    0        // 25088  patch_grad row-sums, pa[p*128 + b]
#define APOOL_OFF 25600    // 588    attack_w mean-pool, k = c*196 + px*14 + py
#define MA_OFF    26624    // 588    masked attack pool
#define IPOOL_OFF 28672    // 75264  input mean-pool [128 b][588 k]
#define PL_OFF    106496   // 1048576 logits partials [8 ksplit][128 b][1024 n]

typedef float v4f __attribute__((ext_vector_type(4)));

__device__ __forceinline__ float hsum4(v4f v) { return (v.x + v.y) + (v.z + v.w); }

// ---------------------------------------------------------------------------
// K1: both 77MB streams, nontemporal loads, max-depth batches.
//   blocks [0,784):     patch_grad row sums — one wave per 8 rows; 24 float4
//                       nt loads issued as one batch before consumption.
//   blocks [784,2139):  input/attack mean-pool — one wave per (img,px) strip,
//                       16-load nt batch.
// History: 6 structural variants (serial, LDS-staged, autonomous, dbuf,
// pinned batches) land 55-59 us; nt loads: ~40 us (skip L2/L3 allocation ->
// no thrash against harness reset writeback). waves/EU=3 and nt stores (R7)
// were neutral/negative -> reverted to this R6-best config.
__global__ __launch_bounds__(256, 2) void k1_main(
    const float* __restrict__ inputs,
    const float* __restrict__ patch_grad,
    const float* __restrict__ attack_w,
    float* __restrict__ ws)
{
  const int bid  = blockIdx.x;
  const int lane = threadIdx.x & 63;

  if (bid < 784) {
    const int w  = bid * 4 + (threadIdx.x >> 6);   // 0..3135
    const int R0 = w * 8;                           // 8 rows of 768 floats
    const v4f* src = (const v4f*)patch_grad + (size_t)R0 * 192 + lane;

    v4f v[24];
    #pragma unroll
    for (int j = 0; j < 24; ++j)
      v[j] = __builtin_nontemporal_load(src + (size_t)j * 64);
    __builtin_amdgcn_sched_barrier(0);

    float s[8];
    #pragma unroll
    for (int k = 0; k < 8; ++k)
      s[k] = hsum4(v[3 * k]) + hsum4(v[3 * k + 1]) + hsum4(v[3 * k + 2]);

    #pragma unroll
    for (int o = 32; o > 0; o >>= 1) {
      #pragma unroll
      for (int k = 0; k < 8; ++k) s[k] += __shfl_down(s[k], o, 64);
    }
    if (lane == 0) {
      float* pa = ws + PA_OFF;
      #pragma unroll
      for (int k = 0; k < 8; ++k) {
        const int row = R0 + k, b = row / 196, p = row - b * 196;
        pa[p * 128 + b] = s[k];
      }
    }
  } else {
    const int w = (bid - 784) * 4 + (threadIdx.x >> 6);
    if (w >= 5418) return;                        // 387 imgs * 14 px
    const int img = w / 14, px = w - img * 14;
    const float* base = (img < 384)
        ? inputs + (size_t)img * 50176
        : attack_w + (size_t)(img - 384) * 50176;
    const v4f* src = (const v4f*)(base + px * 3584);
    const int cl = (lane < 56) ? lane : 55;       // clamp: no divergent load path

    v4f v[16];
    #pragma unroll
    for (int r = 0; r < 16; ++r)
      v[r] = __builtin_nontemporal_load(src + r * 56 + cl);
    __builtin_amdgcn_sched_barrier(0);

    v4f s = v[0];
    #pragma unroll
    for (int r = 1; r < 16; ++r) s += v[r];
    // sum across the 4 lanes of each py group (lanes 4*py .. 4*py+3)
    s.x += __shfl_xor(s.x, 1); s.y += __shfl_xor(s.y, 1);
    s.z += __shfl_xor(s.z, 1); s.w += __shfl_xor(s.w, 1);
    s.x += __shfl_xor(s.x, 2); s.y += __shfl_xor(s.y, 2);
    s.z += __shfl_xor(s.z, 2); s.w += __shfl_xor(s.w, 2);
    if ((lane & 3) == 0 && lane < 56) {
      const int py = lane >> 2;
      const float ps = ((s.x + s.y) + (s.z + s.w)) * (1.f / 256.f);
      if (img < 384) {
        const int b = img / 3, c = img - b * 3;
        ws[IPOOL_OFF + (size_t)b * 588 + c * 196 + px * 14 + py] = ps;
      } else {
        ws[APOOL_OFF + (img - 384) * 196 + px * 14 + py] = ps;
      }
    }
  }
}

// ---------------------------------------------------------------------------
// K2: reduce pa over b, top-20 rank selection, masked attack pool; zero loss.
__global__ __launch_bounds__(256) void k2_topk(float* __restrict__ ws,
                                               float* __restrict__ d_loss)
{
  __shared__ float sp[196];
  __shared__ float maskp[196];
  const int t = threadIdx.x;
  if (t < 196) {
    const float4* q = (const float4*)(ws + PA_OFF + (size_t)t * 128);
    float4 a = make_float4(0.f, 0.f, 0.f, 0.f);
    #pragma unroll
    for (int j = 0; j < 32; ++j) {
      const float4 v = q[j];
      a.x += v.x; a.y += v.y; a.z += v.z; a.w += v.w;
    }
    sp[t] = (a.x + a.y) + (a.z + a.w);
  }
  if (t == 0) *d_loss = 0.f;
  __syncthreads();
  if (t < 196) {
    const float v = sp[t];
    int cnt = 0;
    for (int j = 0; j < 196; ++j) {
      const float u = sp[j];
      cnt += (u > v || (u == v && j < t)) ? 1 : 0;   // rank with index tie-break
    }
    maskp[t] = (cnt < 20) ? 1.f : 0.f;
  }
  __syncthreads();
  for (int k = t; k < 588; k += 256) {
    const int p = k % 196;
    ws[MA_OFF + k] = maskp[p] * ws[APOOL_OFF + k];
  }
}

// ---------------------------------------------------------------------------
// K3: logits = (ipool + ma) @ w_cls, split-K=8 into partials.
// bid = (bg*16 + nt)*8 + ks : bg in [0,16) (8 b's), nt in [0,16) (64 n's),
// ks in [0,8) (74 k's, last slice 70). LDS tile stride 9 -> <=2-way aliasing
// on staging (free per m136), wave-uniform broadcast on reads.
__global__ __launch_bounds__(256) void k3_gemm(const float* __restrict__ w_cls,
                                               float* __restrict__ ws)
{
  __shared__ __align__(16) float lp[74 * 9];
  const int bid = blockIdx.x;
  const int ks = bid & 7;
  const int nt = (bid >> 3) & 15;
  const int bg = bid >> 7;
  const int t  = threadIdx.x;
  const int kk_max = (ks == 7) ? 70 : 74;
  const float* ipool = ws + IPOOL_OFF;
  const float* ma    = ws + MA_OFF;
  for (int idx = t; idx < 592; idx += 256) {
    const int bb = idx & 7;
    const int kk = idx >> 3;
    const int k  = ks * 74 + kk;
    lp[kk * 9 + bb] = (kk < kk_max)
        ? ipool[(size_t)(bg * 8 + bb) * 588 + k] + ma[k]
        : 0.f;
  }
  __syncthreads();
  const int lane = t & 63, g = t >> 6;
  const int n = nt * 64 + lane;
  const bool valid = n < 1000;
  float a0 = 0, a1 = 0;
  const float* wc = w_cls + (size_t)ks * 74 * 1000 + n;
  #pragma unroll 10
  for (int kk = 0; kk < kk_max; ++kk) {
    const float w = valid ? wc[(size_t)kk * 1000] : 0.f;
    const float2 pv = *(const float2*)&lp[kk * 9 + g * 2];  // wave-uniform -> broadcast
    a0 += pv.x * w; a1 += pv.y * w;
  }
  float* pl = ws + PL_OFF;
  const int rowb = bg * 8 + g * 2;
  pl[(size_t)(ks * 128 + rowb + 0) * 1024 + n] = a0;
  pl[(size_t)(ks * 128 + rowb + 1) * 1024 + n] = a1;
}

// ---------------------------------------------------------------------------
// K4: sum 8 split-K partials -> logits; softmax -> prob (output 0);
// log_softmax(prob) -> ce -> loss atomic.
__global__ __launch_bounds__(256) void k4_softmax(const float* __restrict__ ws,
                                                  const int* __restrict__ targets,
                                                  float* __restrict__ out)
{
  __shared__ float red[4];
  __shared__ float sh_pt;
  const int b = blockIdx.x, t = threadIdx.x;
  const float* pl = ws + PL_OFF;
  float l[4]; bool val[4];
  #pragma unroll
  for (int j = 0; j < 4; ++j) {
    const int n = j * 256 + t;
    val[j] = (n < 1000);
    float s = -INFINITY;
    if (val[j]) {
      s = 0.f;
      #pragma unroll
      for (int ks = 0; ks < 8; ++ks) s += pl[(size_t)(ks * 128 + b) * 1024 + n];
    }
    l[j] = s;
  }
  float m = fmaxf(fmaxf(l[0], l[1]), fmaxf(l[2], l[3]));
  #pragma unroll
  for (int o = 32; o > 0; o >>= 1) m = fmaxf(m, __shfl_down(m, o, 64));
  if ((t & 63) == 0) red[t >> 6] = m;
  __syncthreads();
  const float m1 = fmaxf(fmaxf(red[0], red[1]), fmaxf(red[2], red[3]));
  __syncthreads();
  float e[4]; float s = 0.f;
  #pragma unroll
  for (int j = 0; j < 4; ++j) { e[j] = val[j] ? expf(l[j] - m1) : 0.f; s += e[j]; }
  #pragma unroll
  for (int o = 32; o > 0; o >>= 1) s += __shfl_down(s, o, 64);
  if ((t & 63) == 0) red[t >> 6] = s;
  __syncthreads();
  const float S1 = red[0] + red[1] + red[2] + red[3];
  __syncthreads();
  const float inv = 1.f / S1;
  const int tgt = targets[b];
  float p[4];
  #pragma unroll
  for (int j = 0; j < 4; ++j) {
    const int n = j * 256 + t;
    if (val[j]) {
      p[j] = e[j] * inv;
      out[(size_t)b * 1000 + n] = p[j];
      if (n == tgt) sh_pt = p[j];
    } else {
      p[j] = -INFINITY;
    }
  }
  float m2 = fmaxf(fmaxf(p[0], p[1]), fmaxf(p[2], p[3]));
  #pragma unroll
  for (int o = 32; o > 0; o >>= 1) m2 = fmaxf(m2, __shfl_down(m2, o, 64));
  if ((t & 63) == 0) red[t >> 6] = m2;
  __syncthreads();
  const float M2 = fmaxf(fmaxf(red[0], red[1]), fmaxf(red[2], red[3]));
  __syncthreads();
  float s2 = 0.f;
  #pragma unroll
  for (int j = 0; j < 4; ++j) s2 += val[j] ? expf(p[j] - M2) : 0.f;
  #pragma unroll
  for (int o = 32; o > 0; o >>= 1) s2 += __shfl_down(s2, o, 64);
  if ((t & 63) == 0) red[t >> 6] = s2;
  __syncthreads();
  if (t == 0) {
    const float S2 = red[0] + red[1] + red[2] + red[3];
    const float lse2 = M2 + logf(S2);
    atomicAdd(out + 128000, (sh_pt - lse2) * (1.f / 128.f));
  }
}

// ---------------------------------------------------------------------------
extern "C" void kernel_launch(void* const* d_in, const int* in_sizes, int n_in,
                              void* d_out, int out_size, void* d_ws, size_t ws_size,
                              hipStream_t stream) {
  const float* inputs     = (const float*)d_in[0];
  const float* patch_grad = (const float*)d_in[1];
  const float* attack_w   = (const float*)d_in[2];
  const float* w_cls      = (const float*)d_in[3];
  const int*   targets    = (const int*)d_in[4];
  float* out = (float*)d_out;
  float* ws  = (float*)d_ws;

  hipLaunchKernelGGL(k1_main,  dim3(2139), dim3(256), 0, stream,
                     inputs, patch_grad, attack_w, ws);
  hipLaunchKernelGGL(k2_topk,  dim3(1),    dim3(256), 0, stream, ws, out + 128000);
  hipLaunchKernelGGL(k3_gemm,  dim3(2048), dim3(256), 0, stream, w_cls, ws);
  hipLaunchKernelGGL(k4_softmax, dim3(128), dim3(256), 0, stream, ws, targets, out);
}